// Round 4
// baseline (210.995 us; speedup 1.0000x reference)
//
#include <hip/hip_runtime.h>
#include <stdint.h>

// NeRF segmented cumprod — two-pass reduce-then-scan, blocked per-thread
// ranges with ALL loads batched up-front (deep MLP: 16 independent vector
// loads in flight per wave; round-3 post-mortem showed VGPR=20 had the
// compiler serializing loads => latency-bound at 2.6 TB/s effective).
//
// Combine op (associative, NON-commutative):
//   (va,fa) (+) (vb,fb) = (fb ? vb : va*vb, fa|fb)

#define BLOCK 256
#define PT 32                    // elements per thread (blocked)
#define NV (PT / 4)              // float4/int4 vectors per thread = 8
#define CHUNK (BLOCK * PT)       // 8192 elements per block
#define NWAVE (BLOCK / 64)

struct Pair { float v; int f; };

__device__ __forceinline__ Pair seg_combine(Pair a, Pair b) {
    Pair r;
    r.v = b.f ? b.v : (a.v * b.v);
    r.f = a.f | b.f;
    return r;
}

// ---------------------------------------------------------------------------
// Pass 1: per-chunk segmented aggregate (+ alphainv default for empty rays).
// ---------------------------------------------------------------------------
__global__ __launch_bounds__(BLOCK, 4)
void nerf_reduce(const float* __restrict__ alpha, const int* __restrict__ ray_id,
                 float2* __restrict__ agg, float* __restrict__ alphainv,
                 int N_ray, int n) {
    const int c = blockIdx.x, t = threadIdx.x;
    const long gstart = (long)c * CHUNK + (long)t * PT;

    { // alphainv default = cumprod[0] (ref: last_idx=0 for empty rays)
        int gid = c * BLOCK + t;
        if (gid < N_ray) alphainv[gid] = (1.0f - alpha[0]) + 1e-11f;
    }

    Pair run; run.v = 1.0f; run.f = 0;

    if (gstart + PT <= (long)n) {
        // ---- hot path: batch ALL loads (16 independent dwordx4) ----
        float4 AV[NV]; int4 RV[NV];
        #pragma unroll
        for (int q = 0; q < NV; ++q) {
            AV[q] = *(const float4*)(alpha  + gstart + 4 * q);
            RV[q] = *(const int4*)  (ray_id + gstart + 4 * q);
        }
        int prev = (gstart > 0) ? ray_id[gstart - 1] : -1;

        #pragma unroll
        for (int q = 0; q < NV; ++q) {
            const float4 av = AV[q]; const int4 rv = RV[q];
            Pair e;
            e.v = (1.0f - av.x) + 1e-11f; e.f = (rv.x != prev); run = seg_combine(run, e);
            e.v = (1.0f - av.y) + 1e-11f; e.f = (rv.y != rv.x); run = seg_combine(run, e);
            e.v = (1.0f - av.z) + 1e-11f; e.f = (rv.z != rv.y); run = seg_combine(run, e);
            e.v = (1.0f - av.w) + 1e-11f; e.f = (rv.w != rv.z); run = seg_combine(run, e);
            prev = rv.w;
        }
    } else if (gstart < (long)n) {
        int prev = (gstart > 0) ? ray_id[gstart - 1] : -1;
        for (int k = 0; k < PT; ++k) {
            long g = gstart + k;
            if (g < n) {
                int r = ray_id[g];
                Pair e; e.v = (1.0f - alpha[g]) + 1e-11f; e.f = (r != prev);
                prev = r;
                run = seg_combine(run, e);
            }
        }
    }

    // wave-ordered tree reduce (lane 0's dependency tree stays in range)
    #pragma unroll
    for (int off = 1; off < 64; off <<= 1) {
        Pair o;
        o.v = __shfl_down(run.v, off);
        o.f = __shfl_down(run.f, off);
        run = seg_combine(run, o);
    }

    __shared__ float s_wv[NWAVE];
    __shared__ int   s_wf[NWAVE];
    const int lane = t & 63, w = t >> 6;
    if (lane == 0) { s_wv[w] = run.v; s_wf[w] = run.f; }
    __syncthreads();
    if (t == 0) {
        Pair acc; acc.v = s_wv[0]; acc.f = s_wf[0];
        #pragma unroll
        for (int ww = 1; ww < NWAVE; ++ww) {
            Pair e; e.v = s_wv[ww]; e.f = s_wf[ww];
            acc = seg_combine(acc, e);
        }
        agg[c] = make_float2(acc.v, __int_as_float(acc.f));
    }
}

__global__ void nerf_init_rest(const float* __restrict__ alpha,
                               float* __restrict__ alphainv_tail, int count) {
    int i = blockIdx.x * blockDim.x + threadIdx.x;
    if (i < count) alphainv_tail[i] = (1.0f - alpha[0]) + 1e-11f;
}

// ---------------------------------------------------------------------------
// Pass 2: scan + apply. Chunk prefix = plain backward read over agg[] until a
// reset flag (depth ~1: avg seg len 256 << CHUNK 8192). A/R held in registers
// across both sweeps. Seg-END scatter recast as seg-START scatter:
// at each flag (g>0), alphainv[ray_id[g-1]] = trans(g) = cumprod[g-1];
// plus the global last element writes alphainv[ray_id[n-1]] = cumprod[n-1].
// ---------------------------------------------------------------------------
__global__ __launch_bounds__(BLOCK, 3)
void nerf_apply(const float* __restrict__ alpha, const int* __restrict__ ray_id,
                const float2* __restrict__ agg,
                float* __restrict__ weights, float* __restrict__ alphainv, int n) {
    __shared__ float s_wv[NWAVE];
    __shared__ int   s_wf[NWAVE];
    __shared__ float s_pv;
    __shared__ int   s_pf;

    const int c = blockIdx.x, t = threadIdx.x;
    const int lane = t & 63, w = t >> 6;
    const long gstart = (long)c * CHUNK + (long)t * PT;

    // chunk prefix: plain backward read, depth ~1 (overlaps others' loads)
    if (t == 0) {
        Pair pre; pre.v = 1.0f; pre.f = 0;
        for (int j = c - 1; j >= 0; --j) {
            float2 g = agg[j];
            Pair e; e.v = g.x; e.f = __float_as_int(g.y);
            pre = (j == c - 1) ? e : seg_combine(e, pre);
            if (pre.f) break;
        }
        s_pv = pre.v; s_pf = pre.f;
    }

    const bool full = (gstart + PT) <= (long)n;
    float4 AV[NV]; int4 RV[NV];
    if (full) {
        #pragma unroll
        for (int q = 0; q < NV; ++q) {
            AV[q] = *(const float4*)(alpha  + gstart + 4 * q);
            RV[q] = *(const int4*)  (ray_id + gstart + 4 * q);
        }
    } else {
        #pragma unroll
        for (int q = 0; q < NV; ++q) {
            float aa[4]; int rr[4];
            #pragma unroll
            for (int k = 0; k < 4; ++k) {
                long g = gstart + 4 * q + k;
                aa[k] = (g < n) ? alpha[g]  : 0.0f;
                rr[k] = (g < n) ? ray_id[g] : -2;
            }
            AV[q] = make_float4(aa[0], aa[1], aa[2], aa[3]);
            RV[q] = make_int4(rr[0], rr[1], rr[2], rr[3]);
        }
    }
    const int prev0 = (gstart > 0 && gstart < (long)n) ? ray_id[gstart - 1] : -1;

    // ---- thread-local aggregate ----
    Pair loc; loc.v = 1.0f; loc.f = 0;
    {
        int prev = prev0;
        #pragma unroll
        for (int q = 0; q < NV; ++q) {
            const float4 av = AV[q]; const int4 rv = RV[q];
            if (full) {
                Pair e;
                e.v = (1.0f - av.x) + 1e-11f; e.f = (rv.x != prev); loc = seg_combine(loc, e);
                e.v = (1.0f - av.y) + 1e-11f; e.f = (rv.y != rv.x); loc = seg_combine(loc, e);
                e.v = (1.0f - av.z) + 1e-11f; e.f = (rv.z != rv.y); loc = seg_combine(loc, e);
                e.v = (1.0f - av.w) + 1e-11f; e.f = (rv.w != rv.z); loc = seg_combine(loc, e);
                prev = rv.w;
            } else {
                const float aa[4] = {av.x, av.y, av.z, av.w};
                const int   rr[4] = {rv.x, rv.y, rv.z, rv.w};
                #pragma unroll
                for (int k = 0; k < 4; ++k) {
                    long g = gstart + 4 * q + k;
                    if (g < n) {
                        Pair e; e.v = (1.0f - aa[k]) + 1e-11f; e.f = (rr[k] != prev);
                        prev = rr[k];
                        loc = seg_combine(loc, e);
                    }
                }
            }
        }
    }

    // ---- wave inclusive scan over thread aggregates ----
    Pair inc = loc;
    #pragma unroll
    for (int off = 1; off < 64; off <<= 1) {
        Pair o;
        o.v = __shfl_up(inc.v, off);
        o.f = __shfl_up(inc.f, off);
        if (lane >= off) inc = seg_combine(o, inc);
    }
    Pair lexcl;
    {
        float uv = __shfl_up(inc.v, 1);
        int   uf = __shfl_up(inc.f, 1);
        if (lane == 0) { lexcl.v = 1.0f; lexcl.f = 0; }
        else           { lexcl.v = uv;   lexcl.f = uf; }
    }
    if (lane == 63) { s_wv[w] = inc.v; s_wf[w] = inc.f; }
    __syncthreads();

    Pair base; base.v = s_pv; base.f = s_pf;      // chunk prefix
    #pragma unroll
    for (int ww = 0; ww < NWAVE; ++ww) {          // + earlier waves, in order
        if (ww < w) {
            Pair e; e.v = s_wv[ww]; e.f = s_wf[ww];
            base = seg_combine(base, e);
        }
    }
    Pair P = seg_combine(base, lexcl);            // exclusive prefix at elem 0

    // ---- apply sweep (register-only except scatters/stores) ----
    {
        int prevRid = prev0;
        #pragma unroll
        for (int q = 0; q < NV; ++q) {
            const float4 av = AV[q]; const int4 rv = RV[q];
            const long e0 = gstart + 4 * q;
            if (full) {
                float w0, w1, w2, w3;
                // elem 0
                int f = (rv.x != prevRid);
                w0 = av.x * P.v;
                if (f && e0 > 0) alphainv[prevRid] = P.v;
                { Pair e; e.v = (1.0f - av.x) + 1e-11f; e.f = f; P = seg_combine(P, e); }
                if (e0 == (long)n - 1) alphainv[rv.x] = P.v;
                // elem 1
                f = (rv.y != rv.x);
                w1 = av.y * P.v;
                if (f) alphainv[rv.x] = P.v;
                { Pair e; e.v = (1.0f - av.y) + 1e-11f; e.f = f; P = seg_combine(P, e); }
                if (e0 + 1 == (long)n - 1) alphainv[rv.y] = P.v;
                // elem 2
                f = (rv.z != rv.y);
                w2 = av.z * P.v;
                if (f) alphainv[rv.y] = P.v;
                { Pair e; e.v = (1.0f - av.z) + 1e-11f; e.f = f; P = seg_combine(P, e); }
                if (e0 + 2 == (long)n - 1) alphainv[rv.z] = P.v;
                // elem 3
                f = (rv.w != rv.z);
                w3 = av.w * P.v;
                if (f) alphainv[rv.z] = P.v;
                { Pair e; e.v = (1.0f - av.w) + 1e-11f; e.f = f; P = seg_combine(P, e); }
                if (e0 + 3 == (long)n - 1) alphainv[rv.w] = P.v;

                *(float4*)(weights + e0) = make_float4(w0, w1, w2, w3);
            } else {
                const float aa[4] = {av.x, av.y, av.z, av.w};
                const int   rr[4] = {rv.x, rv.y, rv.z, rv.w};
                #pragma unroll
                for (int k = 0; k < 4; ++k) {
                    long g = e0 + k;
                    if (g < n) {
                        int f = (rr[k] != prevRid);
                        float wv = aa[k] * P.v;
                        if (f && g > 0) alphainv[prevRid] = P.v;
                        { Pair e; e.v = (1.0f - aa[k]) + 1e-11f; e.f = f; P = seg_combine(P, e); }
                        if (g == (long)n - 1) alphainv[rr[k]] = P.v;
                        weights[g] = wv;
                        prevRid = rr[k];
                    }
                }
            }
            if (full) prevRid = rv.w;
        }
    }
}

extern "C" void kernel_launch(void* const* d_in, const int* in_sizes, int n_in,
                              void* d_out, int out_size, void* d_ws, size_t ws_size,
                              hipStream_t stream) {
    const float* alpha  = (const float*)d_in[0];
    const int*   ray_id = (const int*)d_in[1];
    const int n     = in_sizes[0];
    const int N_ray = out_size - n;          // avoids device read of d_in[2]

    float* weights  = (float*)d_out;
    float* alphainv = weights + n;
    float2* agg     = (float2*)d_ws;         // nchunks * 8B aggregates

    const int nchunks = (n + CHUNK - 1) / CHUNK;

    nerf_reduce<<<nchunks, BLOCK, 0, stream>>>(alpha, ray_id, agg, alphainv, N_ray, n);
    if (N_ray > nchunks * BLOCK) {           // not hit at this size; same branch every call
        int extra = N_ray - nchunks * BLOCK;
        nerf_init_rest<<<(extra + BLOCK - 1) / BLOCK, BLOCK, 0, stream>>>(
            alpha, alphainv + nchunks * BLOCK, extra);
    }
    nerf_apply<<<nchunks, BLOCK, 0, stream>>>(alpha, ray_id, agg, weights, alphainv, n);
}